// Round 3
// baseline (151.607 us; speedup 1.0000x reference)
//
#include <hip/hip_runtime.h>
#include <hip/hip_bf16.h>

typedef __bf16 bf16_t;
typedef __bf16 bf16x8 __attribute__((ext_vector_type(8)));
typedef float  f32x4  __attribute__((ext_vector_type(4)));

static constexpr int PEW = 1023;  // 2*PE_MAX-1

enum { EPI_NONE = 0, EPI_BIASN = 1, EPI_REL = 2 };

#define GLDS(gsrc, ldst)                                                              \
  __builtin_amdgcn_global_load_lds(                                                   \
      (const __attribute__((address_space(1))) unsigned int*)(gsrc),                  \
      (__attribute__((address_space(3))) unsigned int*)(ldst), 16, 0, 0)

// ---------------- fused fp32->bf16 convert for query & value ----------------
__global__ void k_convert2(const float* __restrict__ a, bf16_t* __restrict__ da,
                           const float* __restrict__ b, bf16_t* __restrict__ db, int n8) {
  int i = blockIdx.x * blockDim.x + threadIdx.x;
  const float* s; bf16_t* d;
  if (i < n8) { s = a; d = da; } else { s = b; d = db; i -= n8; }
  const float4* p = reinterpret_cast<const float4*>(s) + 2 * (long)i;
  float4 x = p[0], y = p[1];
  bf16x8 o;
  o[0] = (bf16_t)x.x; o[1] = (bf16_t)x.y; o[2] = (bf16_t)x.z; o[3] = (bf16_t)x.w;
  o[4] = (bf16_t)y.x; o[5] = (bf16_t)y.y; o[6] = (bf16_t)y.z; o[7] = (bf16_t)y.w;
  reinterpret_cast<bf16x8*>(d)[i] = o;
}

// ---------------- merged 5-way weight transpose (+scale) ----------------
struct TArgs {
  const float* src[5];
  bf16_t* dst[5];
  int C[5], Ct[5], off[5], blk0[6];
  float scale[5];
};
__global__ void k_transpose5(TArgs ta) {
  __shared__ float tile[32][33];
  const int bid = blockIdx.x;
  int s = 0;
  while (bid >= ta.blk0[s + 1]) ++s;
  const int bi = bid - ta.blk0[s];
  const int Ct = ta.Ct[s];
  const int c0 = (bi % Ct) * 32, r0 = (bi / Ct) * 32;
  const int C = ta.C[s];
  const float* src = ta.src[s];
  const int lx = threadIdx.x & 31, ly = threadIdx.x >> 5;
  #pragma unroll
  for (int i = 0; i < 32; i += 8)
    tile[ly + i][lx] = src[(long)(r0 + ly + i) * C + (c0 + lx)];
  __syncthreads();
  const float sc = ta.scale[s];
  bf16_t* dst = ta.dst[s];
  const int off = ta.off[s];
  #pragma unroll
  for (int i = 0; i < 32; i += 8)
    dst[(long)(c0 + ly + i) * 1024 + off + (r0 + lx)] = (bf16_t)(tile[lx][ly + i] * sc);
}

// ---------------- m97-structure GEMM: (MI*32)x128 tile, BK=32, global_load_lds ----------------
template<int MI, int EPI, bool OUT_F32>
__global__ __launch_bounds__(256)
void k_gemm_st(const bf16_t* __restrict__ A_, const bf16_t* __restrict__ B_,
               void* __restrict__ C_, const float* __restrict__ bias,
               int K, int lda, int ldb, int ldc,
               int ZN, long sAb, long sAn, long sBb, long sBn, long sCb, long sCn) {
  __shared__ bf16_t lsA[MI * 1024];
  __shared__ bf16_t lsB[4096];
  const int z = blockIdx.z, zb = z / ZN, zn = z - zb * ZN;
  const int t = threadIdx.x, lane = t & 63, wid = t >> 6;
  const int wr = wid >> 1, wc = wid & 1;
  const int m0 = blockIdx.x * (MI * 32), n0 = blockIdx.y * 128;
  const int lhi = lane >> 4, llo = lane & 15;

  const bf16_t* Ab = A_ + zb * sAb + zn * sAn + (long)m0 * lda;
  const bf16_t* Bb = B_ + zb * sBb + zn * sBn + (long)n0 * ldb;

  const int e0 = t * 8,        r0s = e0 >> 5, c0s = e0 & 31;
  const int e1 = (256 + t) * 8, r1s = e1 >> 5, c1s = e1 & 31;
  bf16_t* lA0 = lsA + wid * 512;
  bf16_t* lA1 = lsA + 2048 + wid * 512;
  bf16_t* lB0 = lsB + wid * 512;
  bf16_t* lB1 = lsB + 2048 + wid * 512;

  f32x4 acc[MI][4] = {};

  for (int k0 = 0; k0 < K; k0 += 32) {
    GLDS(Ab + (long)r0s * lda + k0 + c0s, lA0);
    if constexpr (MI == 4) GLDS(Ab + (long)r1s * lda + k0 + c1s, lA1);
    GLDS(Bb + (long)r0s * ldb + k0 + c0s, lB0);
    GLDS(Bb + (long)r1s * ldb + k0 + c1s, lB1);
    __syncthreads();
    bf16x8 a[MI], b[4];
    #pragma unroll
    for (int mi = 0; mi < MI; ++mi)
      a[mi] = *reinterpret_cast<const bf16x8*>(lsA + (wr * (MI * 16) + mi * 16 + llo) * 32 + lhi * 8);
    #pragma unroll
    for (int ni = 0; ni < 4; ++ni)
      b[ni] = *reinterpret_cast<const bf16x8*>(lsB + (wc * 64 + ni * 16 + llo) * 32 + lhi * 8);
    #pragma unroll
    for (int mi = 0; mi < MI; ++mi)
      #pragma unroll
      for (int ni = 0; ni < 4; ++ni)
        acc[mi][ni] = __builtin_amdgcn_mfma_f32_16x16x32_bf16(a[mi], b[ni], acc[mi][ni], 0, 0, 0);
    __syncthreads();
  }

  float* Cf = (float*)C_;
  bf16_t* Cb = (bf16_t*)C_;
  const long coff = zb * sCb + zn * sCn;
  #pragma unroll
  for (int mi = 0; mi < MI; ++mi) {
    #pragma unroll
    for (int ni = 0; ni < 4; ++ni) {
      #pragma unroll
      for (int r = 0; r < 4; ++r) {
        const int m = m0 + wr * (MI * 16) + mi * 16 + lhi * 4 + r;
        const int n = n0 + wc * 64 + ni * 16 + llo;
        float v = acc[mi][ni][r];
        if constexpr (EPI == EPI_BIASN) v += bias[n];
        if constexpr (EPI == EPI_REL) {
          int idx = n - m + 511;
          idx = idx < 0 ? 0 : (idx > PEW - 1 ? PEW - 1 : idx);
          v += bias[zn * PEW + idx];
        }
        if constexpr (OUT_F32) Cf[coff + (long)m * ldc + n] = v;
        else                   Cb[coff + (long)m * ldc + n] = (bf16_t)v;
      }
    }
  }
}

// ---------------- packed projection GEMMs (qb | kb | vbT^T) in one launch ----------------
struct ProjItem {
  const bf16_t* A; const bf16_t* B; bf16_t* C; const float* bias;
  float bscale; int ldc; int Nt; int writeT;
};
struct ProjArgs { ProjItem it[3]; };

__global__ __launch_bounds__(256)
void k_gemm_proj(ProjArgs pa) {
  const ProjItem it = pa.it[blockIdx.z];
  if ((int)blockIdx.y >= it.Nt) return;
  __shared__ bf16_t lsA[4096];
  __shared__ bf16_t lsB[4096];
  const int t = threadIdx.x, lane = t & 63, wid = t >> 6;
  const int wr = wid >> 1, wc = wid & 1;
  const int m0 = blockIdx.x * 128, n0 = blockIdx.y * 128;
  const int lhi = lane >> 4, llo = lane & 15;

  const bf16_t* Ab = it.A + (long)m0 * 1024;
  const bf16_t* Bb = it.B + (long)n0 * 1024;

  const int e0 = t * 8,        r0s = e0 >> 5, c0s = e0 & 31;
  const int e1 = (256 + t) * 8, r1s = e1 >> 5, c1s = e1 & 31;
  bf16_t* lA0 = lsA + wid * 512;
  bf16_t* lA1 = lsA + 2048 + wid * 512;
  bf16_t* lB0 = lsB + wid * 512;
  bf16_t* lB1 = lsB + 2048 + wid * 512;

  f32x4 acc[4][4] = {};

  for (int k0 = 0; k0 < 1024; k0 += 32) {
    GLDS(Ab + (long)r0s * 1024 + k0 + c0s, lA0);
    GLDS(Ab + (long)r1s * 1024 + k0 + c1s, lA1);
    GLDS(Bb + (long)r0s * 1024 + k0 + c0s, lB0);
    GLDS(Bb + (long)r1s * 1024 + k0 + c1s, lB1);
    __syncthreads();
    bf16x8 a[4], b[4];
    #pragma unroll
    for (int mi = 0; mi < 4; ++mi)
      a[mi] = *reinterpret_cast<const bf16x8*>(lsA + (wr * 64 + mi * 16 + llo) * 32 + lhi * 8);
    #pragma unroll
    for (int ni = 0; ni < 4; ++ni)
      b[ni] = *reinterpret_cast<const bf16x8*>(lsB + (wc * 64 + ni * 16 + llo) * 32 + lhi * 8);
    #pragma unroll
    for (int mi = 0; mi < 4; ++mi)
      #pragma unroll
      for (int ni = 0; ni < 4; ++ni)
        acc[mi][ni] = __builtin_amdgcn_mfma_f32_16x16x32_bf16(a[mi], b[ni], acc[mi][ni], 0, 0, 0);
    __syncthreads();
  }

  #pragma unroll
  for (int mi = 0; mi < 4; ++mi) {
    #pragma unroll
    for (int ni = 0; ni < 4; ++ni) {
      #pragma unroll
      for (int r = 0; r < 4; ++r) {
        const int m = m0 + wr * 64 + mi * 16 + lhi * 4 + r;
        const int n = n0 + wc * 64 + ni * 16 + llo;
        float v = acc[mi][ni][r] + it.bias[n] * it.bscale;
        if (it.writeT) it.C[(long)n * it.ldc + m] = (bf16_t)v;
        else           it.C[(long)m * it.ldc + n] = (bf16_t)v;
      }
    }
  }
}

// ---------------- in-place row softmax over bf16 logits (512 cols) ----------------
__global__ void k_softmax(bf16_t* __restrict__ sc) {
  const int row  = blockIdx.x * 4 + (threadIdx.x >> 6);
  const int lane = threadIdx.x & 63;
  bf16x8* p = reinterpret_cast<bf16x8*>(sc + (long)row * 512) + lane;
  bf16x8 v = *p;
  float f[8];
  float mx = -1e30f;
  #pragma unroll
  for (int i = 0; i < 8; ++i) { f[i] = (float)v[i]; mx = fmaxf(mx, f[i]); }
  #pragma unroll
  for (int off = 32; off; off >>= 1) mx = fmaxf(mx, __shfl_xor(mx, off));
  float s = 0.f;
  #pragma unroll
  for (int i = 0; i < 8; ++i) { f[i] = __expf(f[i] - mx); s += f[i]; }
  #pragma unroll
  for (int off = 32; off; off >>= 1) s += __shfl_xor(s, off);
  const float inv = 1.f / s;
  bf16x8 o;
  #pragma unroll
  for (int i = 0; i < 8; ++i) o[i] = (bf16_t)(f[i] * inv);
  *p = o;
}

// ---------------- PV v2: split-K=4 + LDS tree reduce ----------------
// z = b*16+head (head<8: reuse fp32 A; else bf16 softmax scores).
// block 256 = 4 waves; each wave: full 64x64 tile over K-slice of 128 (unroll 4).
// grid (8, 1, 128) = 1024 blocks; LDS 2x64x68 f32 = 34 KB -> 4 blocks/CU.
__global__ __launch_bounds__(256, 4)
void k_pv(const float* __restrict__ reuse, const bf16_t* __restrict__ sc,
          const bf16_t* __restrict__ vbT, bf16_t* __restrict__ om) {
  __shared__ float red[2][64][68];
  const int z = blockIdx.z;
  const int b = z >> 4, head = z & 15;
  const bool isReuse = head < 8;
  const int lane = threadIdx.x & 63, w = threadIdx.x >> 6;
  const int m0 = blockIdx.x * 64;
  const int lhi = lane >> 4, llo = lane & 15;
  const int ks = w * 128;

  const float*  Af = reuse + (long)b * 2097152 + (long)head * 262144;
  const bf16_t* Ab = sc    + (long)b * 2097152 + (long)(head - 8) * 262144;
  const bf16_t* Bp = vbT + (long)(head * 64) * 4096 + b * 512;

  f32x4 acc[4][4] = {};

  #pragma unroll
  for (int kq = 0; kq < 4; ++kq) {
    const int kk = ks + kq * 32 + lhi * 8;
    bf16x8 a[4], bb[4];
    #pragma unroll
    for (int mi = 0; mi < 4; ++mi) {
      const long row = m0 + mi * 16 + llo;
      if (isReuse) {
        const float4* p = reinterpret_cast<const float4*>(Af + row * 512 + kk);
        float4 x = p[0], y = p[1];
        bf16x8 tv;
        tv[0] = (bf16_t)x.x; tv[1] = (bf16_t)x.y; tv[2] = (bf16_t)x.z; tv[3] = (bf16_t)x.w;
        tv[4] = (bf16_t)y.x; tv[5] = (bf16_t)y.y; tv[6] = (bf16_t)y.z; tv[7] = (bf16_t)y.w;
        a[mi] = tv;
      } else {
        a[mi] = *reinterpret_cast<const bf16x8*>(Ab + row * 512 + kk);
      }
    }
    #pragma unroll
    for (int ni = 0; ni < 4; ++ni)
      bb[ni] = *reinterpret_cast<const bf16x8*>(Bp + (long)(ni * 16 + llo) * 4096 + kk);
    #pragma unroll
    for (int mi = 0; mi < 4; ++mi)
      #pragma unroll
      for (int ni = 0; ni < 4; ++ni)
        acc[mi][ni] = __builtin_amdgcn_mfma_f32_16x16x32_bf16(a[mi], bb[ni], acc[mi][ni], 0, 0, 0);
  }

  // tree reduce: waves 2,3 -> LDS; 0,1 merge; 1 -> LDS; 0 merges + stores.
  if (w >= 2) {
    #pragma unroll
    for (int mi = 0; mi < 4; ++mi)
      #pragma unroll
      for (int ni = 0; ni < 4; ++ni)
        #pragma unroll
        for (int r = 0; r < 4; ++r)
          red[w - 2][mi * 16 + lhi * 4 + r][ni * 16 + llo] = acc[mi][ni][r];
  }
  __syncthreads();
  if (w < 2) {
    #pragma unroll
    for (int mi = 0; mi < 4; ++mi)
      #pragma unroll
      for (int ni = 0; ni < 4; ++ni)
        #pragma unroll
        for (int r = 0; r < 4; ++r)
          acc[mi][ni][r] += red[w][mi * 16 + lhi * 4 + r][ni * 16 + llo];
  }
  __syncthreads();
  if (w == 1) {
    #pragma unroll
    for (int mi = 0; mi < 4; ++mi)
      #pragma unroll
      for (int ni = 0; ni < 4; ++ni)
        #pragma unroll
        for (int r = 0; r < 4; ++r)
          red[0][mi * 16 + lhi * 4 + r][ni * 16 + llo] = acc[mi][ni][r];
  }
  __syncthreads();
  if (w == 0) {
    bf16_t* Cb = om + (long)b * 524288 + head * 64;
    #pragma unroll
    for (int mi = 0; mi < 4; ++mi) {
      #pragma unroll
      for (int ni = 0; ni < 4; ++ni) {
        #pragma unroll
        for (int r = 0; r < 4; ++r) {
          const int m = m0 + mi * 16 + lhi * 4 + r;
          const int nn = ni * 16 + llo;
          float v = acc[mi][ni][r] + red[0][mi * 16 + lhi * 4 + r][nn];
          Cb[(long)m * 1024 + nn] = (bf16_t)v;
        }
      }
    }
  }
}

extern "C" void kernel_launch(void* const* d_in, const int* in_sizes, int n_in,
                              void* d_out, int out_size, void* d_ws, size_t ws_size,
                              hipStream_t stream) {
  const float* query = (const float*)d_in[0];
  const float* value = (const float*)d_in[1];
  const float* reuse = (const float*)d_in[2];
  const float* Wq    = (const float*)d_in[3];
  const float* bq    = (const float*)d_in[4];
  const float* Wk    = (const float*)d_in[5];
  const float* bk    = (const float*)d_in[6];
  const float* Wv    = (const float*)d_in[7];
  const float* bv    = (const float*)d_in[8];
  const float* pe    = (const float*)d_in[9];
  const float* WoR   = (const float*)d_in[10];
  const float* WoN   = (const float*)d_in[11];
  const float* bo    = (const float*)d_in[12];
  float* out = (float*)d_out;
  (void)in_sizes; (void)n_in; (void)out_size; (void)ws_size;

  char* w = (char*)d_ws;
  bf16_t* qx  = (bf16_t*)(w);                 // [4096][1024]
  bf16_t* vx  = (bf16_t*)(w + (8L  << 20));   // [4096][1024]
  bf16_t* WqT = (bf16_t*)(w + (16L << 20));   // [512][1024] (pre-scaled by 1/8)
  bf16_t* WkT = (bf16_t*)(w + (17L << 20));   // [512][1024]
  bf16_t* WvT = (bf16_t*)(w + (18L << 20));   // [1024][1024]
  bf16_t* WoT = (bf16_t*)(w + (20L << 20));   // [1024][1024]
  bf16_t* qb  = (bf16_t*)(w + (22L << 20));   // [4096][512]
  bf16_t* kb  = (bf16_t*)(w + (26L << 20));   // [4096][512]
  bf16_t* vbT = (bf16_t*)(w + (30L << 20));   // [1024][4096]
  bf16_t* sc  = (bf16_t*)(w + (38L << 20));   // [8][8][512][512]
  bf16_t* om  = (bf16_t*)(w + (70L << 20));   // [4096][1024]

  // 1) convert query+value to bf16 (single launch)
  k_convert2<<<4096, 256, 0, stream>>>(query, qx, value, vx, 524288);

  // 2) all weight transposes (single launch); q-scale folded into WqT
  TArgs ta;
  ta.src[0] = Wq;  ta.dst[0] = WqT; ta.C[0] = 512;  ta.Ct[0] = 16; ta.off[0] = 0;   ta.scale[0] = 0.125f;
  ta.src[1] = Wk;  ta.dst[1] = WkT; ta.C[1] = 512;  ta.Ct[1] = 16; ta.off[1] = 0;   ta.scale[1] = 1.f;
  ta.src[2] = Wv;  ta.dst[2] = WvT; ta.C[2] = 1024; ta.Ct[2] = 32; ta.off[2] = 0;   ta.scale[2] = 1.f;
  ta.src[3] = WoR; ta.dst[3] = WoT; ta.C[3] = 1024; ta.Ct[3] = 32; ta.off[3] = 0;   ta.scale[3] = 1.f;
  ta.src[4] = WoN; ta.dst[4] = WoT; ta.C[4] = 1024; ta.Ct[4] = 32; ta.off[4] = 512; ta.scale[4] = 1.f;
  ta.blk0[0] = 0; ta.blk0[1] = 512; ta.blk0[2] = 1024; ta.blk0[3] = 2048; ta.blk0[4] = 2560; ta.blk0[5] = 3072;
  k_transpose5<<<3072, 256, 0, stream>>>(ta);

  // 3) packed projections
  ProjArgs pa;
  pa.it[0] = { qx, WqT, qb,  bq, 0.125f, 512,  4, 0 };
  pa.it[1] = { vx, WkT, kb,  bk, 1.f,    512,  4, 0 };
  pa.it[2] = { vx, WvT, vbT, bv, 1.f,    4096, 8, 1 };
  k_gemm_proj<<<dim3(32, 8, 3), 256, 0, stream>>>(pa);

  // 4) scores = qb_slice @ kb_slice^T + relpos bias -> bf16 logits
  k_gemm_st<4, EPI_REL, false><<<dim3(4, 4, 64), 256, 0, stream>>>(
      qb, kb, sc, pe, 64, 512, 512, 512, 8,
      262144L, 64L, 262144L, 64L, 2097152L, 262144L);

  // 5) softmax in place
  k_softmax<<<8192, 256, 0, stream>>>(sc);

  // 6) out_mid = [reuse @ v_reuse | P @ v_new]  (split-K PV)
  k_pv<<<dim3(8, 1, 128), 256, 0, stream>>>(reuse, sc, vbT, om);

  // 7) out = om @ WoT^T + bo (fp32 out)
  k_gemm_st<2, EPI_BIASN, true><<<dim3(64, 8, 1), 256, 0, stream>>>(
      om, WoT, out, bo, 1024, 1024, 1024, 1024, 1,
      0L, 0L, 0L, 0L, 0L, 0L);
}

// Round 4
// 131.423 us; speedup vs baseline: 1.1536x; 1.1536x over previous
//
#include <hip/hip_runtime.h>
#include <hip/hip_bf16.h>

typedef __bf16 bf16_t;
typedef __bf16 bf16x8 __attribute__((ext_vector_type(8)));
typedef float  f32x4  __attribute__((ext_vector_type(4)));

enum { EPI_NONE = 0, EPI_BIASN = 1, EPI_REL = 2 };

#define GLDS(gsrc, ldst)                                                              \
  __builtin_amdgcn_global_load_lds(                                                   \
      (const __attribute__((address_space(1))) unsigned int*)(gsrc),                  \
      (__attribute__((address_space(3))) unsigned int*)(ldst), 16, 0, 0)

// ---------------- fused fp32->bf16 convert for query & value ----------------
__global__ void k_convert2(const float* __restrict__ a, bf16_t* __restrict__ da,
                           const float* __restrict__ b, bf16_t* __restrict__ db, int n8) {
  int i = blockIdx.x * blockDim.x + threadIdx.x;
  const float* s; bf16_t* d;
  if (i < n8) { s = a; d = da; } else { s = b; d = db; i -= n8; }
  const float4* p = reinterpret_cast<const float4*>(s) + 2 * (long)i;
  float4 x = p[0], y = p[1];
  bf16x8 o;
  o[0] = (bf16_t)x.x; o[1] = (bf16_t)x.y; o[2] = (bf16_t)x.z; o[3] = (bf16_t)x.w;
  o[4] = (bf16_t)y.x; o[5] = (bf16_t)y.y; o[6] = (bf16_t)y.z; o[7] = (bf16_t)y.w;
  reinterpret_cast<bf16x8*>(d)[i] = o;
}

// ---------------- merged 5-way weight transpose (+scale) ----------------
struct TArgs {
  const float* src[5];
  bf16_t* dst[5];
  int C[5], Ct[5], off[5], blk0[6];
  float scale[5];
};
__global__ void k_transpose5(TArgs ta) {
  __shared__ float tile[32][33];
  const int bid = blockIdx.x;
  int s = 0;
  while (bid >= ta.blk0[s + 1]) ++s;
  const int bi = bid - ta.blk0[s];
  const int Ct = ta.Ct[s];
  const int c0 = (bi % Ct) * 32, r0 = (bi / Ct) * 32;
  const int C = ta.C[s];
  const float* src = ta.src[s];
  const int lx = threadIdx.x & 31, ly = threadIdx.x >> 5;
  #pragma unroll
  for (int i = 0; i < 32; i += 8)
    tile[ly + i][lx] = src[(long)(r0 + ly + i) * C + (c0 + lx)];
  __syncthreads();
  const float sc = ta.scale[s];
  bf16_t* dst = ta.dst[s];
  const int off = ta.off[s];
  #pragma unroll
  for (int i = 0; i < 32; i += 8)
    dst[(long)(c0 + ly + i) * 1024 + off + (r0 + lx)] = (bf16_t)(tile[lx][ly + i] * sc);
}

// ---------------- m97-structure GEMM (used for final out-proj) ----------------
template<int MI, int EPI, bool OUT_F32>
__global__ __launch_bounds__(256)
void k_gemm_st(const bf16_t* __restrict__ A_, const bf16_t* __restrict__ B_,
               void* __restrict__ C_, const float* __restrict__ bias,
               int K, int lda, int ldb, int ldc,
               int ZN, long sAb, long sAn, long sBb, long sBn, long sCb, long sCn) {
  __shared__ bf16_t lsA[MI * 1024];
  __shared__ bf16_t lsB[4096];
  const int z = blockIdx.z, zb = z / ZN, zn = z - zb * ZN;
  const int t = threadIdx.x, lane = t & 63, wid = t >> 6;
  const int wr = wid >> 1, wc = wid & 1;
  const int m0 = blockIdx.x * (MI * 32), n0 = blockIdx.y * 128;
  const int lhi = lane >> 4, llo = lane & 15;

  const bf16_t* Ab = A_ + zb * sAb + zn * sAn + (long)m0 * lda;
  const bf16_t* Bb = B_ + zb * sBb + zn * sBn + (long)n0 * ldb;

  const int e0 = t * 8,        r0s = e0 >> 5, c0s = e0 & 31;
  const int e1 = (256 + t) * 8, r1s = e1 >> 5, c1s = e1 & 31;
  bf16_t* lA0 = lsA + wid * 512;
  bf16_t* lA1 = lsA + 2048 + wid * 512;
  bf16_t* lB0 = lsB + wid * 512;
  bf16_t* lB1 = lsB + 2048 + wid * 512;

  f32x4 acc[MI][4] = {};

  for (int k0 = 0; k0 < K; k0 += 32) {
    GLDS(Ab + (long)r0s * lda + k0 + c0s, lA0);
    if constexpr (MI == 4) GLDS(Ab + (long)r1s * lda + k0 + c1s, lA1);
    GLDS(Bb + (long)r0s * ldb + k0 + c0s, lB0);
    GLDS(Bb + (long)r1s * ldb + k0 + c1s, lB1);
    __syncthreads();
    bf16x8 a[MI], b[4];
    #pragma unroll
    for (int mi = 0; mi < MI; ++mi)
      a[mi] = *reinterpret_cast<const bf16x8*>(lsA + (wr * (MI * 16) + mi * 16 + llo) * 32 + lhi * 8);
    #pragma unroll
    for (int ni = 0; ni < 4; ++ni)
      b[ni] = *reinterpret_cast<const bf16x8*>(lsB + (wc * 64 + ni * 16 + llo) * 32 + lhi * 8);
    #pragma unroll
    for (int mi = 0; mi < MI; ++mi)
      #pragma unroll
      for (int ni = 0; ni < 4; ++ni)
        acc[mi][ni] = __builtin_amdgcn_mfma_f32_16x16x32_bf16(a[mi], b[ni], acc[mi][ni], 0, 0, 0);
    __syncthreads();
  }

  float* Cf = (float*)C_;
  bf16_t* Cb = (bf16_t*)C_;
  const long coff = zb * sCb + zn * sCn;
  #pragma unroll
  for (int mi = 0; mi < MI; ++mi) {
    #pragma unroll
    for (int ni = 0; ni < 4; ++ni) {
      #pragma unroll
      for (int r = 0; r < 4; ++r) {
        const int m = m0 + wr * (MI * 16) + mi * 16 + lhi * 4 + r;
        const int n = n0 + wc * 64 + ni * 16 + llo;
        float v = acc[mi][ni][r];
        if constexpr (EPI == EPI_BIASN) v += bias[n];
        if constexpr (OUT_F32) Cf[coff + (long)m * ldc + n] = v;
        else                   Cb[coff + (long)m * ldc + n] = (bf16_t)v;
      }
    }
  }
}

// ---------------- packed projection GEMMs (qb | kb | vbT^T) in one launch ----------------
struct ProjItem {
  const bf16_t* A; const bf16_t* B; bf16_t* C; const float* bias;
  float bscale; int ldc; int Nt; int writeT;
};
struct ProjArgs { ProjItem it[3]; };

__global__ __launch_bounds__(256)
void k_gemm_proj(ProjArgs pa) {
  const ProjItem it = pa.it[blockIdx.z];
  if ((int)blockIdx.y >= it.Nt) return;
  __shared__ bf16_t lsA[4096];
  __shared__ bf16_t lsB[4096];
  const int t = threadIdx.x, lane = t & 63, wid = t >> 6;
  const int wr = wid >> 1, wc = wid & 1;
  const int m0 = blockIdx.x * 128, n0 = blockIdx.y * 128;
  const int lhi = lane >> 4, llo = lane & 15;

  const bf16_t* Ab = it.A + (long)m0 * 1024;
  const bf16_t* Bb = it.B + (long)n0 * 1024;

  const int e0 = t * 8,        r0s = e0 >> 5, c0s = e0 & 31;
  const int e1 = (256 + t) * 8, r1s = e1 >> 5, c1s = e1 & 31;
  bf16_t* lA0 = lsA + wid * 512;
  bf16_t* lA1 = lsA + 2048 + wid * 512;
  bf16_t* lB0 = lsB + wid * 512;
  bf16_t* lB1 = lsB + 2048 + wid * 512;

  f32x4 acc[4][4] = {};

  for (int k0 = 0; k0 < 1024; k0 += 32) {
    GLDS(Ab + (long)r0s * 1024 + k0 + c0s, lA0);
    GLDS(Ab + (long)r1s * 1024 + k0 + c1s, lA1);
    GLDS(Bb + (long)r0s * 1024 + k0 + c0s, lB0);
    GLDS(Bb + (long)r1s * 1024 + k0 + c1s, lB1);
    __syncthreads();
    bf16x8 a[4], b[4];
    #pragma unroll
    for (int mi = 0; mi < 4; ++mi)
      a[mi] = *reinterpret_cast<const bf16x8*>(lsA + (wr * 64 + mi * 16 + llo) * 32 + lhi * 8);
    #pragma unroll
    for (int ni = 0; ni < 4; ++ni)
      b[ni] = *reinterpret_cast<const bf16x8*>(lsB + (wc * 64 + ni * 16 + llo) * 32 + lhi * 8);
    #pragma unroll
    for (int mi = 0; mi < 4; ++mi)
      #pragma unroll
      for (int ni = 0; ni < 4; ++ni)
        acc[mi][ni] = __builtin_amdgcn_mfma_f32_16x16x32_bf16(a[mi], b[ni], acc[mi][ni], 0, 0, 0);
    __syncthreads();
  }

  #pragma unroll
  for (int mi = 0; mi < 4; ++mi) {
    #pragma unroll
    for (int ni = 0; ni < 4; ++ni) {
      #pragma unroll
      for (int r = 0; r < 4; ++r) {
        const int m = m0 + wr * 64 + mi * 16 + lhi * 4 + r;
        const int n = n0 + wc * 64 + ni * 16 + llo;
        float v = acc[mi][ni][r] + it.bias[n] * it.bscale;
        if (it.writeT) it.C[(long)n * it.ldc + m] = (bf16_t)v;
        else           it.C[(long)m * it.ldc + n] = (bf16_t)v;
      }
    }
  }
}

// ---------------- fused attention for new heads: scores + bias + softmax + PV ----------------
// grid (8 t-tiles, 64 bh), block 256 = 4 waves, each wave 16 t-rows, full S=512.
// Q/K/V fragments direct from global (L2-resident slices); P staged per-wave in LDS.
__global__ __launch_bounds__(256, 2)
void k_fattn(const bf16_t* __restrict__ qb, const bf16_t* __restrict__ kb,
             const bf16_t* __restrict__ vbT, const float* __restrict__ pe,
             bf16_t* __restrict__ om) {
  __shared__ float pes[1024];
  __shared__ bf16_t plds[4][16][520];   // pad 8 -> uniform b128 access
  const int bh = blockIdx.y;
  const int b = bh >> 3, h = bh & 7;
  const int lane = threadIdx.x & 63, w = threadIdx.x >> 6;
  const int lhi = lane >> 4, llo = lane & 15;
  const int t0 = blockIdx.x * 64 + w * 16;

  for (int i = threadIdx.x; i < 1023; i += 256) pes[i] = pe[h * 1023 + i];
  __syncthreads();

  // Q fragments (A operand): rows t0+llo, k = c*32 + lhi*8
  const bf16_t* Qb = qb + ((long)(b * 512 + t0 + llo)) * 512 + h * 64;
  bf16x8 qf0 = *reinterpret_cast<const bf16x8*>(Qb + lhi * 8);
  bf16x8 qf1 = *reinterpret_cast<const bf16x8*>(Qb + 32 + lhi * 8);

  // QK^T: acc[st] covers s = st*16 + llo (cols), t = t0 + lhi*4 + r (rows)
  const bf16_t* Kb = kb + ((long)(b * 512)) * 512 + h * 64;
  f32x4 acc[32];
  #pragma unroll
  for (int st = 0; st < 32; ++st) acc[st] = (f32x4){0.f, 0.f, 0.f, 0.f};
  #pragma unroll
  for (int st = 0; st < 32; ++st) {
    const bf16_t* kr = Kb + (long)(st * 16 + llo) * 512;
    bf16x8 kf0 = *reinterpret_cast<const bf16x8*>(kr + lhi * 8);
    bf16x8 kf1 = *reinterpret_cast<const bf16x8*>(kr + 32 + lhi * 8);
    acc[st] = __builtin_amdgcn_mfma_f32_16x16x32_bf16(qf0, kf0, acc[st], 0, 0, 0);
    acc[st] = __builtin_amdgcn_mfma_f32_16x16x32_bf16(qf1, kf1, acc[st], 0, 0, 0);
  }

  // bias + softmax per output row r; row t spread across the 16 llo-lanes
  const int tbase = t0 + lhi * 4;
  #pragma unroll
  for (int r = 0; r < 4; ++r) {
    const int bidx = 511 - (tbase + r) + llo;   // + 16*st, always in [0,1022]
    float m_ = -1e30f;
    #pragma unroll
    for (int st = 0; st < 32; ++st) {
      float v = acc[st][r] + pes[bidx + 16 * st];
      acc[st][r] = v;
      m_ = fmaxf(m_, v);
    }
    m_ = fmaxf(m_, __shfl_xor(m_, 1));
    m_ = fmaxf(m_, __shfl_xor(m_, 2));
    m_ = fmaxf(m_, __shfl_xor(m_, 4));
    m_ = fmaxf(m_, __shfl_xor(m_, 8));
    float s_ = 0.f;
    #pragma unroll
    for (int st = 0; st < 32; ++st) {
      float e = __expf(acc[st][r] - m_);
      acc[st][r] = e;
      s_ += e;
    }
    s_ += __shfl_xor(s_, 1);
    s_ += __shfl_xor(s_, 2);
    s_ += __shfl_xor(s_, 4);
    s_ += __shfl_xor(s_, 8);
    const float inv = 1.f / s_;
    #pragma unroll
    for (int st = 0; st < 32; ++st)
      plds[w][lhi * 4 + r][st * 16 + llo] = (bf16_t)(acc[st][r] * inv);
  }

  // PV: out[t][n] = sum_s P[t][s] * V[n][s];  A = P (rows t = llo), B = V rows (n)
  f32x4 oacc[4] = {};
  const bf16_t* Vb = vbT + (long)(512 + h * 64) * 4096 + b * 512;
  const bf16_t* prow = &plds[w][llo][0];
  #pragma unroll 4
  for (int ks = 0; ks < 16; ++ks) {
    bf16x8 pa = *reinterpret_cast<const bf16x8*>(prow + ks * 32 + lhi * 8);
    #pragma unroll
    for (int ni = 0; ni < 4; ++ni) {
      bf16x8 vf = *reinterpret_cast<const bf16x8*>(Vb + (long)(ni * 16 + llo) * 4096 + ks * 32 + lhi * 8);
      oacc[ni] = __builtin_amdgcn_mfma_f32_16x16x32_bf16(pa, vf, oacc[ni], 0, 0, 0);
    }
  }

  bf16_t* Ob = om + ((long)(b * 512 + tbase)) * 1024 + 512 + h * 64;
  #pragma unroll
  for (int ni = 0; ni < 4; ++ni)
    #pragma unroll
    for (int r = 0; r < 4; ++r)
      Ob[(long)r * 1024 + ni * 16 + llo] = (bf16_t)oacc[ni][r];
}

// ---------------- reuse-heads PV: streaming fp32 A, split-K=4, reg double-buffer ----------------
// grid (16 m-tiles, 64 bh), block 256 = 4 waves (one K-slice of 128 each), 32 rows/wave.
__global__ __launch_bounds__(256, 3)
void k_pvr(const float* __restrict__ reuse, const bf16_t* __restrict__ vbT,
           bf16_t* __restrict__ om) {
  __shared__ float red[2][32][68];
  const int z = blockIdx.y;
  const int b = z >> 3, head = z & 7;
  const int lane = threadIdx.x & 63, w = threadIdx.x >> 6;
  const int lhi = lane >> 4, llo = lane & 15;
  const int m0 = blockIdx.x * 32;
  const int ks0 = w * 128;

  const float*  Af = reuse + (long)b * 2097152 + (long)head * 262144;
  const bf16_t* Bp = vbT + (long)(head * 64) * 4096 + b * 512;

  f32x4 acc[2][4] = {};
  float4 Ax[2][2][2];
  bf16x8 Bx[2][4];

  #define PV_LOAD(kq, buf)                                                              \
    {                                                                                   \
      const int kk = ks0 + (kq) * 32 + lhi * 8;                                         \
      _Pragma("unroll")                                                                 \
      for (int mi = 0; mi < 2; ++mi) {                                                  \
        const float4* p = reinterpret_cast<const float4*>(Af + (long)(m0 + mi * 16 + llo) * 512 + kk); \
        Ax[buf][mi][0] = p[0];                                                          \
        Ax[buf][mi][1] = p[1];                                                          \
      }                                                                                 \
      _Pragma("unroll")                                                                 \
      for (int ni = 0; ni < 4; ++ni)                                                    \
        Bx[buf][ni] = *reinterpret_cast<const bf16x8*>(Bp + (long)(ni * 16 + llo) * 4096 + kk); \
    }

  PV_LOAD(0, 0);
  #pragma unroll
  for (int kq = 0; kq < 4; ++kq) {
    const int cb = kq & 1;
    if (kq < 3) {
      const int nb = (kq + 1) & 1;
      PV_LOAD(kq + 1, nb);
    }
    bf16x8 a[2];
    #pragma unroll
    for (int mi = 0; mi < 2; ++mi) {
      float4 x = Ax[cb][mi][0], y = Ax[cb][mi][1];
      bf16x8 tv;
      tv[0] = (bf16_t)x.x; tv[1] = (bf16_t)x.y; tv[2] = (bf16_t)x.z; tv[3] = (bf16_t)x.w;
      tv[4] = (bf16_t)y.x; tv[5] = (bf16_t)y.y; tv[6] = (bf16_t)y.z; tv[7] = (bf16_t)y.w;
      a[mi] = tv;
    }
    #pragma unroll
    for (int mi = 0; mi < 2; ++mi)
      #pragma unroll
      for (int ni = 0; ni < 4; ++ni)
        acc[mi][ni] = __builtin_amdgcn_mfma_f32_16x16x32_bf16(a[mi], Bx[cb][ni], acc[mi][ni], 0, 0, 0);
  }
  #undef PV_LOAD

  // tree reduce across the 4 K-slices
  if (w >= 2) {
    #pragma unroll
    for (int mi = 0; mi < 2; ++mi)
      #pragma unroll
      for (int ni = 0; ni < 4; ++ni)
        #pragma unroll
        for (int r = 0; r < 4; ++r)
          red[w - 2][mi * 16 + lhi * 4 + r][ni * 16 + llo] = acc[mi][ni][r];
  }
  __syncthreads();
  if (w < 2) {
    #pragma unroll
    for (int mi = 0; mi < 2; ++mi)
      #pragma unroll
      for (int ni = 0; ni < 4; ++ni)
        #pragma unroll
        for (int r = 0; r < 4; ++r)
          acc[mi][ni][r] += red[w][mi * 16 + lhi * 4 + r][ni * 16 + llo];
  }
  __syncthreads();
  if (w == 1) {
    #pragma unroll
    for (int mi = 0; mi < 2; ++mi)
      #pragma unroll
      for (int ni = 0; ni < 4; ++ni)
        #pragma unroll
        for (int r = 0; r < 4; ++r)
          red[0][mi * 16 + lhi * 4 + r][ni * 16 + llo] = acc[mi][ni][r];
  }
  __syncthreads();
  if (w == 0) {
    bf16_t* Cb = om + (long)b * 524288 + head * 64;
    #pragma unroll
    for (int mi = 0; mi < 2; ++mi) {
      #pragma unroll
      for (int ni = 0; ni < 4; ++ni) {
        #pragma unroll
        for (int r = 0; r < 4; ++r) {
          const int m = m0 + mi * 16 + lhi * 4 + r;
          const int nn = ni * 16 + llo;
          float v = acc[mi][ni][r] + red[0][mi * 16 + lhi * 4 + r][nn];
          Cb[(long)m * 1024 + nn] = (bf16_t)v;
        }
      }
    }
  }
}

extern "C" void kernel_launch(void* const* d_in, const int* in_sizes, int n_in,
                              void* d_out, int out_size, void* d_ws, size_t ws_size,
                              hipStream_t stream) {
  const float* query = (const float*)d_in[0];
  const float* value = (const float*)d_in[1];
  const float* reuse = (const float*)d_in[2];
  const float* Wq    = (const float*)d_in[3];
  const float* bq    = (const float*)d_in[4];
  const float* Wk    = (const float*)d_in[5];
  const float* bk    = (const float*)d_in[6];
  const float* Wv    = (const float*)d_in[7];
  const float* bv    = (const float*)d_in[8];
  const float* pe    = (const float*)d_in[9];
  const float* WoR   = (const float*)d_in[10];
  const float* WoN   = (const float*)d_in[11];
  const float* bo    = (const float*)d_in[12];
  float* out = (float*)d_out;
  (void)in_sizes; (void)n_in; (void)out_size; (void)ws_size;

  char* w = (char*)d_ws;
  bf16_t* qx  = (bf16_t*)(w);                 // [4096][1024]
  bf16_t* vx  = (bf16_t*)(w + (8L  << 20));   // [4096][1024]
  bf16_t* WqT = (bf16_t*)(w + (16L << 20));   // [512][1024] (pre-scaled by 1/8)
  bf16_t* WkT = (bf16_t*)(w + (17L << 20));   // [512][1024]
  bf16_t* WvT = (bf16_t*)(w + (18L << 20));   // [1024][1024]
  bf16_t* WoT = (bf16_t*)(w + (20L << 20));   // [1024][1024]
  bf16_t* qb  = (bf16_t*)(w + (22L << 20));   // [4096][512]
  bf16_t* kb  = (bf16_t*)(w + (26L << 20));   // [4096][512]
  bf16_t* vbT = (bf16_t*)(w + (30L << 20));   // [1024][4096]
  bf16_t* om  = (bf16_t*)(w + (38L << 20));   // [4096][1024]

  // 1) convert query+value to bf16
  k_convert2<<<4096, 256, 0, stream>>>(query, qx, value, vx, 524288);

  // 2) weight transposes; q-scale folded into WqT
  TArgs ta;
  ta.src[0] = Wq;  ta.dst[0] = WqT; ta.C[0] = 512;  ta.Ct[0] = 16; ta.off[0] = 0;   ta.scale[0] = 0.125f;
  ta.src[1] = Wk;  ta.dst[1] = WkT; ta.C[1] = 512;  ta.Ct[1] = 16; ta.off[1] = 0;   ta.scale[1] = 1.f;
  ta.src[2] = Wv;  ta.dst[2] = WvT; ta.C[2] = 1024; ta.Ct[2] = 32; ta.off[2] = 0;   ta.scale[2] = 1.f;
  ta.src[3] = WoR; ta.dst[3] = WoT; ta.C[3] = 1024; ta.Ct[3] = 32; ta.off[3] = 0;   ta.scale[3] = 1.f;
  ta.src[4] = WoN; ta.dst[4] = WoT; ta.C[4] = 1024; ta.Ct[4] = 32; ta.off[4] = 512; ta.scale[4] = 1.f;
  ta.blk0[0] = 0; ta.blk0[1] = 512; ta.blk0[2] = 1024; ta.blk0[3] = 2048; ta.blk0[4] = 2560; ta.blk0[5] = 3072;
  k_transpose5<<<3072, 256, 0, stream>>>(ta);

  // 3) packed projections: qb, kb, vbT
  ProjArgs pa;
  pa.it[0] = { qx, WqT, qb,  bq, 0.125f, 512,  4, 0 };
  pa.it[1] = { vx, WkT, kb,  bk, 1.f,    512,  4, 0 };
  pa.it[2] = { vx, WvT, vbT, bv, 1.f,    4096, 8, 1 };
  k_gemm_proj<<<dim3(32, 8, 3), 256, 0, stream>>>(pa);

  // 4) fused new-head attention (scores + bias + softmax + PV)
  k_fattn<<<dim3(8, 64), 256, 0, stream>>>(qb, kb, vbT, pe, om);

  // 5) reuse-heads PV (streaming 67 MB fp32 read)
  k_pvr<<<dim3(16, 64), 256, 0, stream>>>(reuse, vbT, om);

  // 6) out = om @ WoT^T + bo (fp32 out)
  k_gemm_st<2, EPI_BIASN, true><<<dim3(64, 8, 1), 256, 0, stream>>>(
      om, WoT, out, bo, 1024, 1024, 1024, 1024, 1,
      0L, 0L, 0L, 0L, 0L, 0L);
}